// Round 4
// baseline (760.568 us; speedup 1.0000x reference)
//
#include <hip/hip_runtime.h>
#include <hip/hip_bf16.h>

#define D_MODEL 1024
#define NH 16
#define DH 64
#define S_LEN 2048
#define BATCH 2
#define MASK_VAL -1e30f
#define NEG_BIG -3e38f

typedef __attribute__((ext_vector_type(8))) short bf16x8;
typedef __attribute__((ext_vector_type(4))) float f32x4;

static __device__ inline unsigned short f2bf(float f) {
    union { float f; unsigned u; } v; v.f = f;
    unsigned r = v.u + 0x7fffu + ((v.u >> 16) & 1u);
    return (unsigned short)(r >> 16);
}

// Load 8 consecutive f32 (16B-aligned) and round-to-nearest-even into bf16x8.
static __device__ inline bf16x8 cvt8(const float* __restrict__ p) {
    f32x4 a = *(const f32x4*)p;
    f32x4 b = *(const f32x4*)(p + 4);
    bf16x8 r;
    r[0] = (short)f2bf(a[0]); r[1] = (short)f2bf(a[1]);
    r[2] = (short)f2bf(a[2]); r[3] = (short)f2bf(a[3]);
    r[4] = (short)f2bf(b[0]); r[5] = (short)f2bf(b[1]);
    r[6] = (short)f2bf(b[2]); r[7] = (short)f2bf(b[3]);
    return r;
}

// ---------------------------------------------------------------------------
// Kernel 1a: Q projection, all rows:  Q = (x @ Wq^T + bq) / 8
// -> staged as FLOAT32 into d_out ([B*S, D_MODEL]), consumed in place by attn.
// Per-wave 16x64 tile, mfma_f32_16x16x32_bf16, f32 inputs cvt'd at load.
// ---------------------------------------------------------------------------
__global__ __launch_bounds__(256) void proj_q_kernel(
    const float* __restrict__ x,     // [B*S, D_MODEL] f32
    const float* __restrict__ W,     // [D_MODEL, D_MODEL] f32 (row = out col)
    const float* __restrict__ bias,  // [D_MODEL] f32
    float* __restrict__ q_out)       // [B*S, D_MODEL] f32 (= d_out)
{
    const int tid  = threadIdx.x;
    const int wave = tid >> 6;
    const int lane = tid & 63;
    const int quad = lane >> 4;
    const int l16  = lane & 15;

    const int row_base = blockIdx.x * 64 + wave * 16;  // over B*S = 4096
    const int col_base = blockIdx.y * 64;              // over D_MODEL

    f32x4 acc[4] = {};
    const int arow = row_base + l16;

    for (int d = 0; d < D_MODEL; d += 32) {
        bf16x8 a = cvt8(&x[(size_t)arow * D_MODEL + d + quad * 8]);
#pragma unroll
        for (int blk = 0; blk < 4; ++blk) {
            bf16x8 bfr = cvt8(&W[(size_t)(col_base + blk * 16 + l16) * D_MODEL + d + quad * 8]);
            acc[blk] = __builtin_amdgcn_mfma_f32_16x16x32_bf16(a, bfr, acc[blk], 0, 0, 0);
        }
    }
    // C/D layout: col = lane&15 (+16*blk), row = quad*4 + r   [m89-verified]
#pragma unroll
    for (int blk = 0; blk < 4; ++blk) {
        const int col = col_base + blk * 16 + l16;
        const float bval = bias[col];
#pragma unroll
        for (int r = 0; r < 4; ++r) {
            const int row = row_base + quad * 4 + r;
            q_out[(size_t)row * D_MODEL + col] = (acc[blk][r] + bval) * 0.125f;
        }
    }
}

// ---------------------------------------------------------------------------
// Kernel 1b: K/V projection for one pass = batch b0, heads [h0, h0+PH).
// ws layout (bf16): K at [hl][s][dh], V at [(PH+hl)][s][dh]
// ws use = 2*PH*S_LEN*DH bf16 — host-checked against ws_size.
// ---------------------------------------------------------------------------
__global__ __launch_bounds__(256) void proj_kv_kernel(
    const float* __restrict__ k_in,  // [B*S, D_MODEL] f32
    const float* __restrict__ v_in,
    const float* __restrict__ Wk,
    const float* __restrict__ bk,
    const float* __restrict__ Wv,
    const float* __restrict__ bv,
    unsigned short* __restrict__ ws,
    int b0, int h0, int PH)
{
    const int z = blockIdx.z;                  // 0 = K, 1 = V
    const float* x    = z ? v_in : k_in;
    const float* W    = z ? Wv : Wk;
    const float* bias = z ? bv : bk;

    const int tid  = threadIdx.x;
    const int wave = tid >> 6;
    const int lane = tid & 63;
    const int quad = lane >> 4;
    const int l16  = lane & 15;

    const int s_base   = blockIdx.x * 64 + wave * 16;  // local row in batch
    const int hl       = blockIdx.y;                   // local head
    const int col_base = (h0 + hl) * 64;

    f32x4 acc[4] = {};
    const int arow = b0 * S_LEN + s_base + l16;

    for (int d = 0; d < D_MODEL; d += 32) {
        bf16x8 a = cvt8(&x[(size_t)arow * D_MODEL + d + quad * 8]);
#pragma unroll
        for (int blk = 0; blk < 4; ++blk) {
            bf16x8 bfr = cvt8(&W[(size_t)(col_base + blk * 16 + l16) * D_MODEL + d + quad * 8]);
            acc[blk] = __builtin_amdgcn_mfma_f32_16x16x32_bf16(a, bfr, acc[blk], 0, 0, 0);
        }
    }
#pragma unroll
    for (int blk = 0; blk < 4; ++blk) {
        const int col = col_base + blk * 16 + l16;
        const float bval = bias[col];
        const int dh = blk * 16 + l16;           // col_base is a multiple of 64
#pragma unroll
        for (int r = 0; r < 4; ++r) {
            const int s = s_base + quad * 4 + r;
            ws[((size_t)(z * PH + hl) * S_LEN + s) * DH + dh] =
                f2bf(acc[blk][r] + bval);
        }
    }
}

// ---------------------------------------------------------------------------
// Kernel 2: flash attention for one pass (b0, heads [h0,h0+PH)).
// Q read (f32) from d_out — exactly the region this block later overwrites.
// ---------------------------------------------------------------------------
__global__ __launch_bounds__(256) void attn_kernel(
    const unsigned short* __restrict__ ws,    // K/V bf16 as laid out above
    const int* __restrict__ mask,             // [B,S,S] int32, nonzero => masked
    float* __restrict__ out,                  // [B,S,D_MODEL] f32; holds Q/8
    int b0, int h0, int PH)
{
    const int hl    = blockIdx.x;
    const int h     = h0 + hl;
    const int qtile = blockIdx.y;

    const unsigned short* K = ws + (size_t)hl * S_LEN * DH;
    const unsigned short* V = ws + (size_t)(PH + hl) * S_LEN * DH;

    const int tid  = threadIdx.x;
    const int wave = tid >> 6;
    const int lane = tid & 63;
    const int quad = lane >> 4;
    const int l16  = lane & 15;
    const int q0   = qtile * 64;

    __shared__ __align__(16) unsigned short Kt[64 * 64];    // [k][dh]
    __shared__ __align__(16) unsigned short Vt[64 * 64];    // [dh][k] transposed
    __shared__ __align__(16) unsigned short Pt[4][16 * 64]; // per-wave [q][k]

    // Q A-fragments: Q (already /8) lives in `out` at [b0, s, h*64 + dh], f32.
    bf16x8 aq0, aq1;
    {
        const float* qrow =
            out + (size_t)(b0 * S_LEN + q0 + wave * 16 + l16) * D_MODEL + h * DH;
        aq0 = cvt8(qrow + quad * 8);
        aq1 = cvt8(qrow + 32 + quad * 8);
    }

    float m_r[4], l_r[4];
    f32x4 o_acc[4] = {};
#pragma unroll
    for (int r = 0; r < 4; ++r) { m_r[r] = NEG_BIG; l_r[r] = 0.0f; }

    const int qg_base = q0 + wave * 16 + quad * 4;
    const int mask_row0 = (b0 * S_LEN + qg_base) * S_LEN;   // max 8.39M, fits int

    for (int kt = 0; kt < S_LEN / 64; ++kt) {
        // ---- stage K (straight) and V (transposed) from ws (bf16) ----
        {
            const int r = tid >> 2;
            const int c = (tid & 3) * 16;
            const unsigned short* ksrc = K + (size_t)(kt * 64 + r) * DH + c;
            *(bf16x8*)&Kt[r * 64 + c]     = *(const bf16x8*)&ksrc[0];
            *(bf16x8*)&Kt[r * 64 + c + 8] = *(const bf16x8*)&ksrc[8];
            const unsigned short* vsrc = V + (size_t)(kt * 64 + r) * DH + c;
            bf16x8 v0 = *(const bf16x8*)&vsrc[0];
            bf16x8 v1 = *(const bf16x8*)&vsrc[8];
#pragma unroll
            for (int j = 0; j < 8; ++j) {
                Vt[(c + j) * 64 + r]     = (unsigned short)v0[j];
                Vt[(c + 8 + j) * 64 + r] = (unsigned short)v1[j];
            }
        }
        __syncthreads();

        // ---- S = Q K^T : 16 q-rows x 64 k-cols per wave ----
        f32x4 s[4] = {};
#pragma unroll
        for (int blk = 0; blk < 4; ++blk) {
            bf16x8 bk0 = *(const bf16x8*)&Kt[(blk * 16 + l16) * 64 + quad * 8];
            bf16x8 bk1 = *(const bf16x8*)&Kt[(blk * 16 + l16) * 64 + 32 + quad * 8];
            s[blk] = __builtin_amdgcn_mfma_f32_16x16x32_bf16(aq0, bk0, s[blk], 0, 0, 0);
            s[blk] = __builtin_amdgcn_mfma_f32_16x16x32_bf16(aq1, bk1, s[blk], 0, 0, 0);
        }

        // ---- mask ----
#pragma unroll
        for (int blk = 0; blk < 4; ++blk) {
            const int kg = kt * 64 + blk * 16 + l16;
#pragma unroll
            for (int r = 0; r < 4; ++r) {
                if (mask[mask_row0 + r * S_LEN + kg]) s[blk][r] = MASK_VAL;
            }
        }

        // ---- online softmax (row r spans the 16 lanes of this quad) ----
#pragma unroll
        for (int r = 0; r < 4; ++r) {
            float mx = fmaxf(fmaxf(s[0][r], s[1][r]), fmaxf(s[2][r], s[3][r]));
            mx = fmaxf(mx, __shfl_xor(mx, 1, 64));
            mx = fmaxf(mx, __shfl_xor(mx, 2, 64));
            mx = fmaxf(mx, __shfl_xor(mx, 4, 64));
            mx = fmaxf(mx, __shfl_xor(mx, 8, 64));
            const float mnew  = fmaxf(m_r[r], mx);
            const float alpha = __expf(m_r[r] - mnew);
            m_r[r] = mnew;
            l_r[r] *= alpha;
#pragma unroll
            for (int blk = 0; blk < 4; ++blk) o_acc[blk][r] *= alpha;
            float sum = 0.0f;
#pragma unroll
            for (int blk = 0; blk < 4; ++blk) {
                const float p = __expf(s[blk][r] - mnew);
                s[blk][r] = p;
                sum += p;
            }
            sum += __shfl_xor(sum, 1, 64);
            sum += __shfl_xor(sum, 2, 64);
            sum += __shfl_xor(sum, 4, 64);
            sum += __shfl_xor(sum, 8, 64);
            l_r[r] += sum;
        }

        // ---- P (C-layout) -> LDS -> A-layout (m120 pattern) ----
#pragma unroll
        for (int blk = 0; blk < 4; ++blk)
#pragma unroll
            for (int r = 0; r < 4; ++r)
                Pt[wave][(quad * 4 + r) * 64 + blk * 16 + l16] = f2bf(s[blk][r]);
        __syncthreads();

        bf16x8 ap0 = *(const bf16x8*)&Pt[wave][l16 * 64 + quad * 8];
        bf16x8 ap1 = *(const bf16x8*)&Pt[wave][l16 * 64 + 32 + quad * 8];

        // ---- O += P V ----
#pragma unroll
        for (int dblk = 0; dblk < 4; ++dblk) {
            bf16x8 bv0 = *(const bf16x8*)&Vt[(dblk * 16 + l16) * 64 + quad * 8];
            bf16x8 bv1 = *(const bf16x8*)&Vt[(dblk * 16 + l16) * 64 + 32 + quad * 8];
            o_acc[dblk] = __builtin_amdgcn_mfma_f32_16x16x32_bf16(ap0, bv0, o_acc[dblk], 0, 0, 0);
            o_acc[dblk] = __builtin_amdgcn_mfma_f32_16x16x32_bf16(ap1, bv1, o_acc[dblk], 0, 0, 0);
        }
        __syncthreads();
    }

    // ---- epilogue: O / l -> out f32 (overwrites this block's own Q stripe) ----
#pragma unroll
    for (int blk = 0; blk < 4; ++blk) {
#pragma unroll
        for (int r = 0; r < 4; ++r) {
            const int qg = qg_base + r;
            out[((size_t)(b0 * S_LEN) + qg) * D_MODEL + h * DH + blk * 16 + l16] =
                o_acc[blk][r] / l_r[r];
        }
    }
}

extern "C" void kernel_launch(void* const* d_in, const int* in_sizes, int n_in,
                              void* d_out, int out_size, void* d_ws, size_t ws_size,
                              hipStream_t stream) {
    const float* query = (const float*)d_in[0];
    const float* key   = (const float*)d_in[1];
    const float* value = (const float*)d_in[2];
    const int*   mask  = (const int*)d_in[3];
    const float* Wq    = (const float*)d_in[4];
    const float* bq    = (const float*)d_in[5];
    const float* Wk    = (const float*)d_in[6];
    const float* bk    = (const float*)d_in[7];
    const float* Wv    = (const float*)d_in[8];
    const float* bv    = (const float*)d_in[9];

    unsigned short* ws   = (unsigned short*)d_ws;
    float*          outp = (float*)d_out;

    // PH = heads per pass; K+V bf16 for a pass needs 2*PH*S*DH*2 bytes.
    // PH=16 -> 8.39 MB, PH=4 -> 2.10 MB, PH=1 -> 0.52 MB. Largest that fits.
    int PH = 16;
    if (ws_size < (size_t)2 * 16 * S_LEN * DH * sizeof(unsigned short)) PH = 4;
    if (ws_size < (size_t)2 * 4  * S_LEN * DH * sizeof(unsigned short)) PH = 1;

    // Q (f32, pre-scaled) staged into d_out; consumed in place by attn blocks.
    proj_q_kernel<<<dim3(64, 16), 256, 0, stream>>>(query, Wq, bq, outp);

    for (int b0 = 0; b0 < BATCH; ++b0) {
        for (int h0 = 0; h0 < NH; h0 += PH) {
            proj_kv_kernel<<<dim3(S_LEN / 64, PH, 2), 256, 0, stream>>>(
                key, value, Wk, bk, Wv, bv, ws, b0, h0, PH);
            attn_kernel<<<dim3(PH, S_LEN / 64), 256, 0, stream>>>(
                ws, mask, outp, b0, h0, PH);
        }
    }
}

// Round 5
// 436.422 us; speedup vs baseline: 1.7427x; 1.7427x over previous
//
#include <hip/hip_runtime.h>
#include <hip/hip_bf16.h>

#define D_MODEL 1024
#define NH 16
#define DH 64
#define S_LEN 2048
#define BATCH 2
#define MASK_VAL -1e30f
#define NEG_BIG -3e38f

#define KV_HSTRIDE (S_LEN * DH)         // ushorts per head slab
#define WS_V_OFF   (NH * KV_HSTRIDE)    // V^T slab offset in ws (ushorts)
// ws use: 2 * NH * S_LEN * DH * 2B = 8.39 MB (PH=16 path proven in-bounds R4)

typedef __attribute__((ext_vector_type(8))) short bf16x8;
typedef __attribute__((ext_vector_type(4))) float f32x4;

static __device__ inline unsigned short f2bf(float f) {
    union { float f; unsigned u; } v; v.f = f;
    unsigned r = v.u + 0x7fffu + ((v.u >> 16) & 1u);
    return (unsigned short)(r >> 16);
}

static __device__ inline bf16x8 pack8(f32x4 a, f32x4 b) {
    bf16x8 r;
    r[0] = (short)f2bf(a[0]); r[1] = (short)f2bf(a[1]);
    r[2] = (short)f2bf(a[2]); r[3] = (short)f2bf(a[3]);
    r[4] = (short)f2bf(b[0]); r[5] = (short)f2bf(b[1]);
    r[6] = (short)f2bf(b[2]); r[7] = (short)f2bf(b[3]);
    return r;
}

// Load 8 consecutive f32 (16B-aligned) -> bf16x8 (RNE).
static __device__ inline bf16x8 cvt8(const float* __restrict__ p) {
    return pack8(*(const f32x4*)p, *(const f32x4*)(p + 4));
}

// ---------------------------------------------------------------------------
// Fused QKV projection for one batch: 128x128-tile GEMM (m97 structure),
// BK=32, LDS-staged with f32->bf16 cvt at staging.  M=2048 (batch rows),
// N=3072 fused (z = by>>3 selects Q/K/V).  Epilogue:
//   z=0: Q/8 -> d_out f32 [B,S,D_MODEL]   (consumed in place by attn)
//   z=1: K   -> ws bf16 [h][s][dh]
//   z=2: V   -> ws bf16 [h][dh][s]   (pre-transposed for attn's PV B-frags)
// ---------------------------------------------------------------------------
__global__ __launch_bounds__(256) void proj_fused_kernel(
    const float* __restrict__ q_in, const float* __restrict__ k_in,
    const float* __restrict__ v_in,
    const float* __restrict__ Wq, const float* __restrict__ bq,
    const float* __restrict__ Wk, const float* __restrict__ bk,
    const float* __restrict__ Wv, const float* __restrict__ bv,
    float* __restrict__ q_out, unsigned short* __restrict__ ws, int b0)
{
    const int bx = blockIdx.x;          // 16 tiles over batch rows
    const int by = blockIdx.y;          // 24 tiles over fused N=3072
    const int z  = by >> 3;             // 0=Q, 1=K, 2=V (uniform per block)
    const int c0 = (by & 7) * 128;      // col base within this z

    const float* x    = z == 0 ? q_in : (z == 1 ? k_in : v_in);
    const float* W    = z == 0 ? Wq   : (z == 1 ? Wk   : Wv);
    const float* bias = z == 0 ? bq   : (z == 1 ? bk   : bv);

    const int tid  = threadIdx.x;
    const int wave = tid >> 6;
    const int lane = tid & 63;
    const int quad = lane >> 4;
    const int l16  = lane & 15;
    const int m0   = (wave & 1) * 64;
    const int n0   = (wave >> 1) * 64;

    __shared__ __align__(16) unsigned short As[128][32];   // [s_local][k]
    __shared__ __align__(16) unsigned short Bs[128][32];   // [n_local][k]

    const int srow = tid >> 1;            // 0..127
    const int kcol = (tid & 1) * 16;      // 0 or 16
    const float* ag = x + (size_t)(b0 * S_LEN + bx * 128 + srow) * D_MODEL + kcol;
    const float* bg = W + (size_t)(c0 + srow) * D_MODEL + kcol;

    f32x4 acc[4][4] = {};   // [i over m][j over n]

    for (int kk = 0; kk < D_MODEL; kk += 32) {
        // ---- stage A, B: 16 f32 each per thread, cvt once, 2 b128 writes ----
        {
            f32x4 a0 = *(const f32x4*)(ag + kk);
            f32x4 a1 = *(const f32x4*)(ag + kk + 4);
            f32x4 a2 = *(const f32x4*)(ag + kk + 8);
            f32x4 a3 = *(const f32x4*)(ag + kk + 12);
            f32x4 b0 = *(const f32x4*)(bg + kk);
            f32x4 b1 = *(const f32x4*)(bg + kk + 4);
            f32x4 b2 = *(const f32x4*)(bg + kk + 8);
            f32x4 b3 = *(const f32x4*)(bg + kk + 12);
            *(bf16x8*)&As[srow][kcol]     = pack8(a0, a1);
            *(bf16x8*)&As[srow][kcol + 8] = pack8(a2, a3);
            *(bf16x8*)&Bs[srow][kcol]     = pack8(b0, b1);
            *(bf16x8*)&Bs[srow][kcol + 8] = pack8(b2, b3);
        }
        __syncthreads();

        // ---- fragments + 16 MFMA (full BK=32 per instruction) ----
        bf16x8 af[4], bfr[4];
#pragma unroll
        for (int i = 0; i < 4; ++i)
            af[i] = *(const bf16x8*)&As[m0 + i * 16 + l16][quad * 8];
#pragma unroll
        for (int j = 0; j < 4; ++j)
            bfr[j] = *(const bf16x8*)&Bs[n0 + j * 16 + l16][quad * 8];
#pragma unroll
        for (int i = 0; i < 4; ++i)
#pragma unroll
            for (int j = 0; j < 4; ++j)
                acc[i][j] = __builtin_amdgcn_mfma_f32_16x16x32_bf16(
                    af[i], bfr[j], acc[i][j], 0, 0, 0);
        __syncthreads();
    }

    // ---- epilogue.  C layout: row = quad*4 + r, col = l16 (m89-verified) ----
#pragma unroll
    for (int j = 0; j < 4; ++j) {
        const int cl  = c0 + n0 + j * 16 + l16;       // col within z, [0,1024)
        const float bval = bias[cl];
        const int h  = cl >> 6;
        const int dh = cl & 63;
#pragma unroll
        for (int i = 0; i < 4; ++i) {
#pragma unroll
            for (int r = 0; r < 4; ++r) {
                const int s_local = bx * 128 + m0 + i * 16 + quad * 4 + r;
                const float v = acc[i][j][r] + bval;
                if (z == 0) {
                    q_out[(size_t)(b0 * S_LEN + s_local) * D_MODEL + cl] = v * 0.125f;
                } else if (z == 1) {
                    ws[(size_t)h * KV_HSTRIDE + s_local * DH + dh] = f2bf(v);
                } else {
                    ws[WS_V_OFF + (size_t)h * KV_HSTRIDE + dh * S_LEN + s_local] = f2bf(v);
                }
            }
        }
    }
}

// ---------------------------------------------------------------------------
// Flash attention for one batch, all 16 heads.  Block = (h, qtile of 64).
// Q read f32 from d_out (region this block later overwrites).  V^T staged
// with straight vector copies (pre-transposed by proj).
// ---------------------------------------------------------------------------
__global__ __launch_bounds__(256) void attn_kernel(
    const unsigned short* __restrict__ ws,    // K [h][s][dh], V^T [h][dh][s]
    const int* __restrict__ mask,             // [B,S,S] int32, nonzero => masked
    float* __restrict__ out,                  // [B,S,D_MODEL] f32; holds Q/8
    int b0)
{
    const int h     = blockIdx.x;
    const int qtile = blockIdx.y;

    const unsigned short* K  = ws + (size_t)h * KV_HSTRIDE;
    const unsigned short* Vg = ws + WS_V_OFF + (size_t)h * KV_HSTRIDE;

    const int tid  = threadIdx.x;
    const int wave = tid >> 6;
    const int lane = tid & 63;
    const int quad = lane >> 4;
    const int l16  = lane & 15;
    const int q0   = qtile * 64;

    __shared__ __align__(16) unsigned short Kt[64 * 64];    // [k][dh]
    __shared__ __align__(16) unsigned short Vt[64 * 64];    // [dh][k]
    __shared__ __align__(16) unsigned short Pt[4][16 * 64]; // per-wave [q][k]

    bf16x8 aq0, aq1;
    {
        const float* qrow =
            out + (size_t)(b0 * S_LEN + q0 + wave * 16 + l16) * D_MODEL + h * DH;
        aq0 = cvt8(qrow + quad * 8);
        aq1 = cvt8(qrow + 32 + quad * 8);
    }

    float m_r[4], l_r[4];
    f32x4 o_acc[4] = {};
#pragma unroll
    for (int r = 0; r < 4; ++r) { m_r[r] = NEG_BIG; l_r[r] = 0.0f; }

    const int qg_base = q0 + wave * 16 + quad * 4;
    const int mask_row0 = (b0 * S_LEN + qg_base) * S_LEN;

    for (int kt = 0; kt < S_LEN / 64; ++kt) {
        // ---- stage K and V^T (both straight vector copies now) ----
        {
            const int r = tid >> 2;
            const int c = (tid & 3) * 16;
            const unsigned short* ksrc = K + (size_t)(kt * 64 + r) * DH + c;
            *(bf16x8*)&Kt[r * 64 + c]     = *(const bf16x8*)&ksrc[0];
            *(bf16x8*)&Kt[r * 64 + c + 8] = *(const bf16x8*)&ksrc[8];
            const unsigned short* vsrc = Vg + (size_t)r * S_LEN + kt * 64 + c;
            *(bf16x8*)&Vt[r * 64 + c]     = *(const bf16x8*)&vsrc[0];
            *(bf16x8*)&Vt[r * 64 + c + 8] = *(const bf16x8*)&vsrc[8];
        }
        __syncthreads();

        // ---- S = Q K^T ----
        f32x4 s[4] = {};
#pragma unroll
        for (int blk = 0; blk < 4; ++blk) {
            bf16x8 bk0 = *(const bf16x8*)&Kt[(blk * 16 + l16) * 64 + quad * 8];
            bf16x8 bk1 = *(const bf16x8*)&Kt[(blk * 16 + l16) * 64 + 32 + quad * 8];
            s[blk] = __builtin_amdgcn_mfma_f32_16x16x32_bf16(aq0, bk0, s[blk], 0, 0, 0);
            s[blk] = __builtin_amdgcn_mfma_f32_16x16x32_bf16(aq1, bk1, s[blk], 0, 0, 0);
        }

        // ---- mask ----
#pragma unroll
        for (int blk = 0; blk < 4; ++blk) {
            const int kg = kt * 64 + blk * 16 + l16;
#pragma unroll
            for (int r = 0; r < 4; ++r) {
                if (mask[mask_row0 + r * S_LEN + kg]) s[blk][r] = MASK_VAL;
            }
        }

        // ---- online softmax ----
#pragma unroll
        for (int r = 0; r < 4; ++r) {
            float mx = fmaxf(fmaxf(s[0][r], s[1][r]), fmaxf(s[2][r], s[3][r]));
            mx = fmaxf(mx, __shfl_xor(mx, 1, 64));
            mx = fmaxf(mx, __shfl_xor(mx, 2, 64));
            mx = fmaxf(mx, __shfl_xor(mx, 4, 64));
            mx = fmaxf(mx, __shfl_xor(mx, 8, 64));
            const float mnew  = fmaxf(m_r[r], mx);
            const float alpha = __expf(m_r[r] - mnew);
            m_r[r] = mnew;
            l_r[r] *= alpha;
#pragma unroll
            for (int blk = 0; blk < 4; ++blk) o_acc[blk][r] *= alpha;
            float sum = 0.0f;
#pragma unroll
            for (int blk = 0; blk < 4; ++blk) {
                const float p = __expf(s[blk][r] - mnew);
                s[blk][r] = p;
                sum += p;
            }
            sum += __shfl_xor(sum, 1, 64);
            sum += __shfl_xor(sum, 2, 64);
            sum += __shfl_xor(sum, 4, 64);
            sum += __shfl_xor(sum, 8, 64);
            l_r[r] += sum;
        }

        // ---- P (C-layout) -> LDS -> A-layout ----
#pragma unroll
        for (int blk = 0; blk < 4; ++blk)
#pragma unroll
            for (int r = 0; r < 4; ++r)
                Pt[wave][(quad * 4 + r) * 64 + blk * 16 + l16] = f2bf(s[blk][r]);
        __syncthreads();

        bf16x8 ap0 = *(const bf16x8*)&Pt[wave][l16 * 64 + quad * 8];
        bf16x8 ap1 = *(const bf16x8*)&Pt[wave][l16 * 64 + 32 + quad * 8];

        // ---- O += P V ----
#pragma unroll
        for (int dblk = 0; dblk < 4; ++dblk) {
            bf16x8 bv0 = *(const bf16x8*)&Vt[(dblk * 16 + l16) * 64 + quad * 8];
            bf16x8 bv1 = *(const bf16x8*)&Vt[(dblk * 16 + l16) * 64 + 32 + quad * 8];
            o_acc[dblk] = __builtin_amdgcn_mfma_f32_16x16x32_bf16(ap0, bv0, o_acc[dblk], 0, 0, 0);
            o_acc[dblk] = __builtin_amdgcn_mfma_f32_16x16x32_bf16(ap1, bv1, o_acc[dblk], 0, 0, 0);
        }
        __syncthreads();
    }

    // ---- epilogue ----
#pragma unroll
    for (int blk = 0; blk < 4; ++blk) {
#pragma unroll
        for (int r = 0; r < 4; ++r) {
            const int qg = qg_base + r;
            out[((size_t)(b0 * S_LEN) + qg) * D_MODEL + h * DH + blk * 16 + l16] =
                o_acc[blk][r] / l_r[r];
        }
    }
}

extern "C" void kernel_launch(void* const* d_in, const int* in_sizes, int n_in,
                              void* d_out, int out_size, void* d_ws, size_t ws_size,
                              hipStream_t stream) {
    const float* query = (const float*)d_in[0];
    const float* key   = (const float*)d_in[1];
    const float* value = (const float*)d_in[2];
    const int*   mask  = (const int*)d_in[3];
    const float* Wq    = (const float*)d_in[4];
    const float* bq    = (const float*)d_in[5];
    const float* Wk    = (const float*)d_in[6];
    const float* bk    = (const float*)d_in[7];
    const float* Wv    = (const float*)d_in[8];
    const float* bv    = (const float*)d_in[9];

    unsigned short* ws   = (unsigned short*)d_ws;   // 8.39 MB (R4-evidenced fit)
    float*          outp = (float*)d_out;

    for (int b0 = 0; b0 < BATCH; ++b0) {
        proj_fused_kernel<<<dim3(16, 24), 256, 0, stream>>>(
            query, key, value, Wq, bq, Wk, bk, Wv, bv, outp, ws, b0);
        attn_kernel<<<dim3(NH, S_LEN / 64), 256, 0, stream>>>(
            ws, mask, outp, b0);
    }
}

// Round 6
// 329.533 us; speedup vs baseline: 2.3080x; 1.3244x over previous
//
#include <hip/hip_runtime.h>
#include <hip/hip_bf16.h>

#define D_MODEL 1024
#define NH 16
#define DH 64
#define S_LEN 2048
#define BATCH 2
#define MASK_VAL -1e30f
#define NEG_BIG -3e38f

#define KV_HSTRIDE (S_LEN * DH)           // ushorts per head slab
#define WS_V_OFF   (NH * KV_HSTRIDE)      // V^T offset within a batch slab
#define KVB_WORDS  (2 * NH * KV_HSTRIDE)  // ushorts per batch K+V slab (8.39 MB)
#define MB_WORDS   ((S_LEN / 64) * S_LEN) // uint64 mask words per batch (512 KB)

typedef __attribute__((ext_vector_type(8))) short bf16x8;
typedef __attribute__((ext_vector_type(4))) float f32x4;

static __device__ inline unsigned short f2bf(float f) {
    union { float f; unsigned u; } v; v.f = f;
    unsigned r = v.u + 0x7fffu + ((v.u >> 16) & 1u);
    return (unsigned short)(r >> 16);
}
static __device__ inline bf16x8 pack8(f32x4 a, f32x4 b) {
    bf16x8 r;
    r[0] = (short)f2bf(a[0]); r[1] = (short)f2bf(a[1]);
    r[2] = (short)f2bf(a[2]); r[3] = (short)f2bf(a[3]);
    r[4] = (short)f2bf(b[0]); r[5] = (short)f2bf(b[1]);
    r[6] = (short)f2bf(b[2]); r[7] = (short)f2bf(b[3]);
    return r;
}
static __device__ inline bf16x8 cvt8(const float* __restrict__ p) {
    return pack8(*(const f32x4*)p, *(const f32x4*)(p + 4));
}

// ---------------------------------------------------------------------------
// Mask bit-pack: mbits[b_rel][kt][s] = ballot over k-window of 64.
// One wave produces one uint64; coalesced int32 reads.
// ---------------------------------------------------------------------------
__global__ __launch_bounds__(256) void pack_mask_kernel(
    const int* __restrict__ mask, unsigned long long* __restrict__ mbits,
    int b_base)
{
    const int w    = blockIdx.x * 4 + (threadIdx.x >> 6);  // word index (rel)
    const int lane = threadIdx.x & 63;
    const int b    = b_base + (w >> 16);       // MB_WORDS = 65536 per batch
    const int rem  = w & 65535;
    const int kt   = rem >> 11;
    const int s    = rem & 2047;
    const int v = mask[((size_t)b * S_LEN + s) * S_LEN + kt * 64 + lane];
    const unsigned long long bits = __ballot(v != 0);
    if (lane == 0) mbits[w] = bits;
}

// ---------------------------------------------------------------------------
// Fused QKV projection, rows [b_base*2048, (b_base+nb)*2048).
// 128x128 tile, BK=32, LDS padded to 40 (kills 8-way frag-read conflicts).
//   z=0: Q/8 -> d_out f32;  z=1: K -> ws bf16 [b][h][s][dh];
//   z=2: V -> ws bf16 [b][h][dh][s] (pre-transposed)
// ---------------------------------------------------------------------------
__global__ __launch_bounds__(256) void proj_fused_kernel(
    const float* __restrict__ q_in, const float* __restrict__ k_in,
    const float* __restrict__ v_in,
    const float* __restrict__ Wq, const float* __restrict__ bq,
    const float* __restrict__ Wk, const float* __restrict__ bk,
    const float* __restrict__ Wv, const float* __restrict__ bv,
    float* __restrict__ q_out, unsigned short* __restrict__ ws, int b_base)
{
    const int bx = blockIdx.x;          // tiles over rows of this launch
    const int by = blockIdx.y;          // 24 tiles over fused N=3072
    const int z  = by >> 3;
    const int c0 = (by & 7) * 128;

    const float* x    = z == 0 ? q_in : (z == 1 ? k_in : v_in);
    const float* W    = z == 0 ? Wq   : (z == 1 ? Wk   : Wv);
    const float* bias = z == 0 ? bq   : (z == 1 ? bk   : bv);

    const int tid  = threadIdx.x;
    const int wave = tid >> 6;
    const int lane = tid & 63;
    const int quad = lane >> 4;
    const int l16  = lane & 15;
    const int m0   = (wave & 1) * 64;
    const int n0   = (wave >> 1) * 64;

    __shared__ __align__(16) unsigned short As[128][40];   // +8 pad
    __shared__ __align__(16) unsigned short Bs[128][40];

    const int srow = tid >> 1;
    const int kcol = (tid & 1) * 16;
    const int row0 = b_base * S_LEN + bx * 128;            // global row base
    const float* ag = x + (size_t)(row0 + srow) * D_MODEL + kcol;
    const float* bg = W + (size_t)(c0 + srow) * D_MODEL + kcol;

    f32x4 acc[4][4] = {};

    for (int kk = 0; kk < D_MODEL; kk += 32) {
        {
            f32x4 a0 = *(const f32x4*)(ag + kk);
            f32x4 a1 = *(const f32x4*)(ag + kk + 4);
            f32x4 a2 = *(const f32x4*)(ag + kk + 8);
            f32x4 a3 = *(const f32x4*)(ag + kk + 12);
            f32x4 b0 = *(const f32x4*)(bg + kk);
            f32x4 b1 = *(const f32x4*)(bg + kk + 4);
            f32x4 b2 = *(const f32x4*)(bg + kk + 8);
            f32x4 b3 = *(const f32x4*)(bg + kk + 12);
            *(bf16x8*)&As[srow][kcol]     = pack8(a0, a1);
            *(bf16x8*)&As[srow][kcol + 8] = pack8(a2, a3);
            *(bf16x8*)&Bs[srow][kcol]     = pack8(b0, b1);
            *(bf16x8*)&Bs[srow][kcol + 8] = pack8(b2, b3);
        }
        __syncthreads();

        bf16x8 af[4], bfr[4];
#pragma unroll
        for (int i = 0; i < 4; ++i)
            af[i] = *(const bf16x8*)&As[m0 + i * 16 + l16][quad * 8];
#pragma unroll
        for (int j = 0; j < 4; ++j)
            bfr[j] = *(const bf16x8*)&Bs[n0 + j * 16 + l16][quad * 8];
#pragma unroll
        for (int i = 0; i < 4; ++i)
#pragma unroll
            for (int j = 0; j < 4; ++j)
                acc[i][j] = __builtin_amdgcn_mfma_f32_16x16x32_bf16(
                    af[i], bfr[j], acc[i][j], 0, 0, 0);
        __syncthreads();
    }

#pragma unroll
    for (int j = 0; j < 4; ++j) {
        const int cl  = c0 + n0 + j * 16 + l16;
        const float bval = bias[cl];
        const int h  = cl >> 6;
        const int dh = cl & 63;
#pragma unroll
        for (int i = 0; i < 4; ++i) {
#pragma unroll
            for (int r = 0; r < 4; ++r) {
                const int row = row0 + m0 + i * 16 + quad * 4 + r;  // global
                const float v = acc[i][j][r] + bval;
                if (z == 0) {
                    q_out[(size_t)row * D_MODEL + cl] = v * 0.125f;
                } else {
                    const int b_rel = (row >> 11) - b_base;
                    const int s     = row & 2047;
                    unsigned short* slab = ws + (size_t)b_rel * KVB_WORDS;
                    if (z == 1)
                        slab[(size_t)h * KV_HSTRIDE + s * DH + dh] = f2bf(v);
                    else
                        slab[WS_V_OFF + (size_t)h * KV_HSTRIDE + dh * S_LEN + s] = f2bf(v);
                }
            }
        }
    }
}

// ---------------------------------------------------------------------------
// Flash attention.  Block = (h, qtile, b_rel).  LDS rows padded to 72.
// Mask from packed bits (use_bits=1) or raw int32 (fallback).
// ---------------------------------------------------------------------------
__global__ __launch_bounds__(256) void attn_kernel(
    const unsigned short* __restrict__ ws,
    const unsigned long long* __restrict__ mbits,
    const int* __restrict__ mask,
    float* __restrict__ out, int b_base, int use_bits)
{
    const int h     = blockIdx.x;
    const int qtile = blockIdx.y;
    const int bz    = blockIdx.z;
    const int b0    = b_base + bz;

    const unsigned short* K  = ws + (size_t)bz * KVB_WORDS + (size_t)h * KV_HSTRIDE;
    const unsigned short* Vg = K + WS_V_OFF;
    const unsigned long long* mb = mbits + (size_t)bz * MB_WORDS;

    const int tid  = threadIdx.x;
    const int wave = tid >> 6;
    const int lane = tid & 63;
    const int quad = lane >> 4;
    const int l16  = lane & 15;
    const int q0   = qtile * 64;

    __shared__ __align__(16) unsigned short Kt[64][72];
    __shared__ __align__(16) unsigned short Vt[64][72];
    __shared__ __align__(16) unsigned short Pt[4][16 * 72];

    bf16x8 aq0, aq1;
    {
        const float* qrow =
            out + (size_t)(b0 * S_LEN + q0 + wave * 16 + l16) * D_MODEL + h * DH;
        aq0 = cvt8(qrow + quad * 8);
        aq1 = cvt8(qrow + 32 + quad * 8);
    }

    float m_r[4], l_r[4];
    f32x4 o_acc[4] = {};
#pragma unroll
    for (int r = 0; r < 4; ++r) { m_r[r] = NEG_BIG; l_r[r] = 0.0f; }

    const int qg_base = q0 + wave * 16 + quad * 4;
    const int mask_row0 = (b0 * S_LEN + qg_base) * S_LEN;

    for (int kt = 0; kt < S_LEN / 64; ++kt) {
        // ---- stage K and V^T (straight b128 copies, padded rows) ----
        {
            const int r = tid >> 2;
            const int c = (tid & 3) * 16;
            const unsigned short* ksrc = K + (size_t)(kt * 64 + r) * DH + c;
            *(bf16x8*)&Kt[r][c]     = *(const bf16x8*)&ksrc[0];
            *(bf16x8*)&Kt[r][c + 8] = *(const bf16x8*)&ksrc[8];
            const unsigned short* vsrc = Vg + (size_t)r * S_LEN + kt * 64 + c;
            *(bf16x8*)&Vt[r][c]     = *(const bf16x8*)&vsrc[0];
            *(bf16x8*)&Vt[r][c + 8] = *(const bf16x8*)&vsrc[8];
        }
        // ---- fetch mask words early (overlaps staging latency) ----
        unsigned long long wm[4];
        if (use_bits) {
#pragma unroll
            for (int r = 0; r < 4; ++r)
                wm[r] = mb[kt * S_LEN + qg_base + r];   // 16 rows = 1 cache line
        }
        __syncthreads();

        // ---- S = Q K^T ----
        f32x4 s[4] = {};
#pragma unroll
        for (int blk = 0; blk < 4; ++blk) {
            bf16x8 bk0 = *(const bf16x8*)&Kt[blk * 16 + l16][quad * 8];
            bf16x8 bk1 = *(const bf16x8*)&Kt[blk * 16 + l16][32 + quad * 8];
            s[blk] = __builtin_amdgcn_mfma_f32_16x16x32_bf16(aq0, bk0, s[blk], 0, 0, 0);
            s[blk] = __builtin_amdgcn_mfma_f32_16x16x32_bf16(aq1, bk1, s[blk], 0, 0, 0);
        }

        // ---- mask ----
        if (use_bits) {
#pragma unroll
            for (int r = 0; r < 4; ++r) {
                const unsigned lo = (unsigned)wm[r];
                const unsigned hi = (unsigned)(wm[r] >> 32);
#pragma unroll
                for (int blk = 0; blk < 4; ++blk) {
                    const unsigned half = (blk & 2) ? hi : lo;
                    const unsigned sh = ((blk & 1) << 4) + l16;
                    if ((half >> sh) & 1u) s[blk][r] = MASK_VAL;
                }
            }
        } else {
#pragma unroll
            for (int blk = 0; blk < 4; ++blk) {
                const int kg = kt * 64 + blk * 16 + l16;
#pragma unroll
                for (int r = 0; r < 4; ++r)
                    if (mask[mask_row0 + r * S_LEN + kg]) s[blk][r] = MASK_VAL;
            }
        }

        // ---- online softmax ----
#pragma unroll
        for (int r = 0; r < 4; ++r) {
            float mx = fmaxf(fmaxf(s[0][r], s[1][r]), fmaxf(s[2][r], s[3][r]));
            mx = fmaxf(mx, __shfl_xor(mx, 1, 64));
            mx = fmaxf(mx, __shfl_xor(mx, 2, 64));
            mx = fmaxf(mx, __shfl_xor(mx, 4, 64));
            mx = fmaxf(mx, __shfl_xor(mx, 8, 64));
            const float mnew  = fmaxf(m_r[r], mx);
            const float alpha = __expf(m_r[r] - mnew);
            m_r[r] = mnew;
            l_r[r] *= alpha;
#pragma unroll
            for (int blk = 0; blk < 4; ++blk) o_acc[blk][r] *= alpha;
            float sum = 0.0f;
#pragma unroll
            for (int blk = 0; blk < 4; ++blk) {
                const float p = __expf(s[blk][r] - mnew);
                s[blk][r] = p;
                sum += p;
            }
            sum += __shfl_xor(sum, 1, 64);
            sum += __shfl_xor(sum, 2, 64);
            sum += __shfl_xor(sum, 4, 64);
            sum += __shfl_xor(sum, 8, 64);
            l_r[r] += sum;
        }

        // ---- P -> LDS -> A-layout.  Pt is wave-private: NO barrier needed;
        //      compiler-inserted lgkmcnt orders the ds_write -> ds_read. ----
#pragma unroll
        for (int blk = 0; blk < 4; ++blk)
#pragma unroll
            for (int r = 0; r < 4; ++r)
                Pt[wave][(quad * 4 + r) * 72 + blk * 16 + l16] = f2bf(s[blk][r]);

        bf16x8 ap0 = *(const bf16x8*)&Pt[wave][l16 * 72 + quad * 8];
        bf16x8 ap1 = *(const bf16x8*)&Pt[wave][l16 * 72 + 32 + quad * 8];

        // ---- O += P V ----
#pragma unroll
        for (int dblk = 0; dblk < 4; ++dblk) {
            bf16x8 bv0 = *(const bf16x8*)&Vt[dblk * 16 + l16][quad * 8];
            bf16x8 bv1 = *(const bf16x8*)&Vt[dblk * 16 + l16][32 + quad * 8];
            o_acc[dblk] = __builtin_amdgcn_mfma_f32_16x16x32_bf16(ap0, bv0, o_acc[dblk], 0, 0, 0);
            o_acc[dblk] = __builtin_amdgcn_mfma_f32_16x16x32_bf16(ap1, bv1, o_acc[dblk], 0, 0, 0);
        }
        __syncthreads();   // protect Kt/Vt before next restage
    }

#pragma unroll
    for (int blk = 0; blk < 4; ++blk) {
#pragma unroll
        for (int r = 0; r < 4; ++r) {
            const int qg = qg_base + r;
            out[((size_t)(b0 * S_LEN) + qg) * D_MODEL + h * DH + blk * 16 + l16] =
                o_acc[blk][r] / l_r[r];
        }
    }
}

extern "C" void kernel_launch(void* const* d_in, const int* in_sizes, int n_in,
                              void* d_out, int out_size, void* d_ws, size_t ws_size,
                              hipStream_t stream) {
    const float* query = (const float*)d_in[0];
    const float* key   = (const float*)d_in[1];
    const float* value = (const float*)d_in[2];
    const int*   mask  = (const int*)d_in[3];
    const float* Wq    = (const float*)d_in[4];
    const float* bq    = (const float*)d_in[5];
    const float* Wk    = (const float*)d_in[6];
    const float* bk    = (const float*)d_in[7];
    const float* Wv    = (const float*)d_in[8];
    const float* bv    = (const float*)d_in[9];

    unsigned short* ws   = (unsigned short*)d_ws;
    float*          outp = (float*)d_out;

    const size_t KV_BYTES = (size_t)KVB_WORDS * 2;   // 8.39 MB / batch
    const size_t MB_BYTES = (size_t)MB_WORDS * 8;    // 512 KB / batch

    if (ws_size >= 2 * KV_BYTES + 2 * MB_BYTES) {
        // Tier A: both batches in single launches (max parallelism).
        unsigned long long* mbits = (unsigned long long*)(ws + 2 * KVB_WORDS);
        proj_fused_kernel<<<dim3(32, 24), 256, 0, stream>>>(
            query, key, value, Wq, bq, Wk, bk, Wv, bv, outp, ws, 0);
        pack_mask_kernel<<<dim3(2 * MB_WORDS / 4), 256, 0, stream>>>(mask, mbits, 0);
        attn_kernel<<<dim3(NH, S_LEN / 64, 2), 256, 0, stream>>>(
            ws, mbits, mask, outp, 0, 1);
    } else if (ws_size >= KV_BYTES + MB_BYTES) {
        // Tier B: per batch, packed mask.
        unsigned long long* mbits = (unsigned long long*)(ws + KVB_WORDS);
        for (int b0 = 0; b0 < BATCH; ++b0) {
            proj_fused_kernel<<<dim3(16, 24), 256, 0, stream>>>(
                query, key, value, Wq, bq, Wk, bk, Wv, bv, outp, ws, b0);
            pack_mask_kernel<<<dim3(MB_WORDS / 4), 256, 0, stream>>>(mask, mbits, b0);
            attn_kernel<<<dim3(NH, S_LEN / 64, 1), 256, 0, stream>>>(
                ws, mbits, mask, outp, b0, 1);
        }
    } else {
        // Tier C: per batch, raw int mask (R5-proven footprint).
        for (int b0 = 0; b0 < BATCH; ++b0) {
            proj_fused_kernel<<<dim3(16, 24), 256, 0, stream>>>(
                query, key, value, Wq, bq, Wk, bk, Wv, bv, outp, ws, b0);
            attn_kernel<<<dim3(NH, S_LEN / 64, 1), 256, 0, stream>>>(
                ws, (const unsigned long long*)ws, mask, outp, b0, 0);
        }
    }
}